// Round 7
// baseline (144.350 us; speedup 1.0000x reference)
//
#include <hip/hip_runtime.h>
#include <hip/hip_bf16.h>
#include <math.h>

#define HID 128
#define ATT 64
#define HOPS 8
#define T_ 64
#define N_ 64
#define B_ 64
#define L_ 4096

typedef __attribute__((ext_vector_type(8))) short bf16x8;
typedef __attribute__((ext_vector_type(4))) float f32x4;

static constexpr size_t OFF_A     = (size_t)B_ * N_ * T_;              // 262144
static constexpr size_t OFF_NEIGH = OFF_A + (size_t)B_ * HOPS * L_;    // 2359296
static constexpr size_t OFF_PENAL = OFF_NEIGH + (size_t)B_ * L_ * HID; // 35913728

__device__ __forceinline__ unsigned pkbf(float lo, float hi) {
    unsigned a = (unsigned)(unsigned short)__builtin_bit_cast(unsigned short, __float2bfloat16(lo));
    unsigned b = (unsigned)(unsigned short)__builtin_bit_cast(unsigned short, __float2bfloat16(hi));
    return a | (b << 16);
}
__device__ __forceinline__ short f2bf(float x) {
    return __builtin_bit_cast(short, __float2bfloat16(x));
}
__device__ __forceinline__ float bflo(unsigned u) {   // low bf16 -> f32
    return __builtin_bit_cast(float, u << 16);
}
__device__ __forceinline__ float bfhi(unsigned u) {   // high bf16 -> f32
    return __builtin_bit_cast(float, u & 0xffff0000u);
}

// Load/store mapping for a 16-row strip, half hh (hh0 = cols 0..63, hh1 = 64..127):
// j = hh*4 + jl; row = (lane>>3) + 8*(j&1); piece = (lane&7) + 8*(j>>1)  (float4 units)
// -> each instruction: 8 rows x 128B contiguous full cache lines, fully coalesced.
__device__ __forceinline__ void load_half(float4 v[4], const float* sb, int rlo, int plo, int hh) {
    #pragma unroll
    for (int jl = 0; jl < 4; ++jl) {
        const int j = hh * 4 + jl;
        const int row = rlo + 8 * (j & 1);
        const int pc  = plo + 8 * (j >> 1);
        v[jl] = *(const float4*)(sb + row * HID + pc * 4);
    }
}
__device__ __forceinline__ void store_half(const float4 v[4], float* db, int rlo, int plo, int hh) {
    #pragma unroll
    for (int jl = 0; jl < 4; ++jl) {
        const int j = hh * 4 + jl;
        const int row = rlo + 8 * (j & 1);
        const int pc  = plo + 8 * (j >> 1);
        *(float4*)(db + row * HID + pc * 4) = v[jl];
    }
}
__device__ __forceinline__ void pack_half(const float4 v[4], const uint2 npk[8], int hh, uint2 hp[4]) {
    #pragma unroll
    for (int jl = 0; jl < 4; ++jl) {
        const int j = hh * 4 + jl;
        const float n0 = bflo(npk[j].x), n1 = bfhi(npk[j].x);
        const float n2 = bflo(npk[j].y), n3 = bfhi(npk[j].y);
        hp[jl].x = pkbf(v[jl].x * n0, v[jl].y * n1);
        hp[jl].y = pkbf(v[jl].z * n2, v[jl].w * n3);
    }
}

// In-register transpose to A-fragments via bpermute, then 8 MFMA (cols cf*16..).
// af[ks] reg i holds H[row=c][k = ks*32 + g*8 + 2i, +1]; source lane (c&7)*8+2g+(i>>1),
// source pack hp[2*(ks&1) + (c>>3)], u32 half = i&1.
__device__ __forceinline__ void half_mfma(const uint2 hp[4], int hh, int src0, bool hi,
                                          const unsigned* w1p, f32x4 acc[4]) {
    #pragma unroll
    for (int kk = 0; kk < 2; ++kk) {
        const int ks = hh * 2 + kk;
        const int e0 = __shfl((int)hp[2 * kk].x,     src0);
        const int o0 = __shfl((int)hp[2 * kk + 1].x, src0);
        const int e1 = __shfl((int)hp[2 * kk].y,     src0);
        const int o1 = __shfl((int)hp[2 * kk + 1].y, src0);
        const int e2 = __shfl((int)hp[2 * kk].x,     src0 + 1);
        const int o2 = __shfl((int)hp[2 * kk + 1].x, src0 + 1);
        const int e3 = __shfl((int)hp[2 * kk].y,     src0 + 1);
        const int o3 = __shfl((int)hp[2 * kk + 1].y, src0 + 1);
        union { bf16x8 v8; int u[4]; } af;
        af.u[0] = hi ? o0 : e0;
        af.u[1] = hi ? o1 : e1;
        af.u[2] = hi ? o2 : e2;
        af.u[3] = hi ? o3 : e3;
        #pragma unroll
        for (int cf = 0; cf < 4; ++cf) {
            const bf16x8 wf = *reinterpret_cast<const bf16x8*>(w1p + cf * 1088 + ks * 16);
            acc[cf] = __builtin_amdgcn_mfma_f32_16x16x32_bf16(af.v8, wf, acc[cf], 0, 0, 0);
        }
    }
}

// ---------------- K1: barrier-free per-wave strips; shfl transpose; MFMA ----------------
// Grid 1024 x 256thr = 4096 waves; wave (b, q=blk4*4+w) owns strips q*16 + k*1024, k=0..3.
// No block barrier in the loop (W1/W2 staged once). 4 blocks/CU, 16 independent waves/CU.
__global__ __launch_bounds__(256, 4)
void k1_mfma(const float* __restrict__ node, const float* __restrict__ neigh,
             const int* __restrict__ nnum, const float* __restrict__ W1,
             const float* __restrict__ b1, const float* __restrict__ W2,
             const float* __restrict__ b2, float* __restrict__ out)
{
    __shared__ __align__(16) unsigned w1lds[64 * 68];   // 17 KB: W1 bf16 [a][kpair], stride 68
    __shared__ __align__(16) uint4    w2lds[64 * 3];    //  3 KB: per-lane W2 B-frags, stride 3
    __shared__ __align__(16) short    thlds[4][16 * 72];//  9 KB: per-wave tanh tile

    const int tid  = threadIdx.x;
    const int w    = tid >> 6;
    const int lane = tid & 63;
    const int c    = lane & 15;
    const int g    = lane >> 4;
    const int b    = blockIdx.x >> 4;
    const int q    = ((blockIdx.x & 15) << 2) | w;
    const int rlo  = lane >> 3;
    const int plo  = lane & 7;

    // ---- stage W1 -> LDS bf16 ----
    {
        const int a = tid >> 2, qq = tid & 3;
        const float* src = W1 + a * HID + qq * 32;
        float x[32];
        #pragma unroll
        for (int i = 0; i < 8; ++i) *(float4*)&x[i * 4] = *(const float4*)(src + i * 4);
        unsigned* dst = &w1lds[a * 68 + qq * 16];
        #pragma unroll
        for (int i = 0; i < 16; ++i) dst[i] = pkbf(x[2 * i], x[2 * i + 1]);
    }
    // ---- stage W2 B-fragments (identical for every wave) ----
    if (tid < 64) {
        const int cc = tid & 15, gg = tid >> 4;
        #pragma unroll
        for (int ks2 = 0; ks2 < 2; ++ks2) {
            unsigned u[4];
            #pragma unroll
            for (int i = 0; i < 4; ++i) {
                float lo = (cc < 8) ? W2[cc * 64 + ks2 * 32 + gg * 8 + 2 * i]     : 0.f;
                float hh = (cc < 8) ? W2[cc * 64 + ks2 * 32 + gg * 8 + 2 * i + 1] : 0.f;
                u[i] = pkbf(lo, hh);
            }
            uint4 t; t.x = u[0]; t.y = u[1]; t.z = u[2]; t.w = u[3];
            w2lds[tid * 3 + ks2] = t;
        }
    }

    // ---- node rows for this wave (q%4 == w), packed bf16, loop-invariant ----
    uint2 npk[8];
    {
        const float* ndw = node + ((size_t)b * T_ + w * 16) * HID;
        #pragma unroll
        for (int j = 0; j < 8; ++j) {
            const int row = rlo + 8 * (j & 1);
            const int pc  = plo + 8 * (j >> 1);
            float4 nv = *(const float4*)(ndw + row * HID + pc * 4);
            npk[j].x = pkbf(nv.x, nv.y);
            npk[j].y = pkbf(nv.z, nv.w);
        }
    }

    float b1v[4];
    #pragma unroll
    for (int cf = 0; cf < 4; ++cf) b1v[cf] = b1[cf * 16 + c];
    const float b2v = (c < 8) ? b2[c] : 0.f;
    const float inv_scale = rsqrtf((float)nnum[0]);

    const size_t strip0 = ((size_t)b * L_ + (size_t)q * 16) * HID;
    const float* npb = neigh + strip0;
    float*       cpb = out + OFF_NEIGH + strip0;
    float*       s2b = out + OFF_A + (size_t)b * HOPS * L_;

    float4 bufA[4], bufB[4];
    load_half(bufA, npb, rlo, plo, 0);     // strip 0 half A in flight across the barrier

    // LDS-only barrier: publishes W1/W2; does NOT drain vmcnt (loads stay in flight)
    asm volatile("s_waitcnt lgkmcnt(0)" ::: "memory");
    __builtin_amdgcn_s_barrier();

    const int src0 = (c & 7) * 8 + 2 * g;
    const bool hisel = (c >= 8);
    const unsigned* w1p = &w1lds[c * 68 + g * 4];
    short* thw = thlds[w];

    #pragma unroll
    for (int k = 0; k < 4; ++k) {
        const float* sb   = npb + (size_t)k * 1024 * HID;
        float*       cdst = cpb + (size_t)k * 1024 * HID;

        load_half(bufB, sb, rlo, plo, 1);          // half B of this strip in flight

        f32x4 acc[4];
        #pragma unroll
        for (int cf = 0; cf < 4; ++cf) acc[cf] = (f32x4){0.f, 0.f, 0.f, 0.f};

        uint2 hp[4];
        pack_half(bufA, npk, 0, hp);               // waits bufA only (partial vmcnt)
        store_half(bufA, cdst, rlo, plo, 0);       // bit-exact copy-out, full lines
        half_mfma(hp, 0, src0, hisel, w1p, acc);   // ks 0,1

        if (k < 3)                                  // next strip half A, one phase ahead
            load_half(bufA, npb + (size_t)(k + 1) * 1024 * HID, rlo, plo, 0);

        pack_half(bufB, npk, 1, hp);
        store_half(bufB, cdst, rlo, plo, 1);
        half_mfma(hp, 1, src0, hisel, w1p, acc);   // ks 2,3

        // ---- epilogue: tanh -> per-wave LDS -> s2 MFMA -> store ----
        #pragma unroll
        for (int cf = 0; cf < 4; ++cf) {
            #pragma unroll
            for (int jj = 0; jj < 4; ++jj) {
                float th = (acc[cf][jj] + b1v[cf]) * inv_scale;
                th = 1.0f - 2.0f / (__expf(2.0f * th) + 1.0f);   // tanh, inf-safe
                thw[(g * 4 + jj) * 72 + cf * 16 + c] = f2bf(th);
            }
        }
        f32x4 acc2 = (f32x4){0.f, 0.f, 0.f, 0.f};
        #pragma unroll
        for (int ks2 = 0; ks2 < 2; ++ks2) {
            bf16x8 pa = *reinterpret_cast<const bf16x8*>(&thw[c * 72 + ks2 * 32 + g * 8]);
            bf16x8 wf = *reinterpret_cast<const bf16x8*>(&w2lds[lane * 3 + ks2]);
            acc2 = __builtin_amdgcn_mfma_f32_16x16x32_bf16(pa, wf, acc2, 0, 0, 0);
        }
        if (c < 8) {
            float4 o;
            o.x = acc2[0] + b2v; o.y = acc2[1] + b2v;
            o.z = acc2[2] + b2v; o.w = acc2[3] + b2v;
            *(float4*)&s2b[(size_t)c * L_ + q * 16 + k * 1024 + g * 4] = o;
        }
    }
}

// ---------------- reductions helpers ----------------
__device__ __forceinline__ float waveMax(float v) {
    #pragma unroll
    for (int o = 32; o > 0; o >>= 1) v = fmaxf(v, __shfl_xor(v, o));
    return v;
}
__device__ __forceinline__ float waveSum(float v) {
    #pragma unroll
    for (int o = 32; o > 0; o >>= 1) v += __shfl_xor(v, o);
    return v;
}

// ---------------- K2: per-(b,h) softmax stats + zero aat accumulators ----------------
__global__ __launch_bounds__(256)
void k2_stats(const float* __restrict__ out, float* __restrict__ stats, float* __restrict__ aat)
{
    const int bh = blockIdx.x;                         // 0..511
    const int tid = threadIdx.x;
    if (bh == 0) {
        for (int i = tid; i < B_ * 36; i += 256) aat[i] = 0.f;
    }
    const float* row = out + OFF_A + (size_t)bh * L_;
    __shared__ float red[8];
    float m = -3.4e38f;
    for (int i = tid; i < L_; i += 256) m = fmaxf(m, row[i]);
    m = waveMax(m);
    if ((tid & 63) == 0) red[tid >> 6] = m;
    __syncthreads();
    const float M = fmaxf(fmaxf(red[0], red[1]), fmaxf(red[2], red[3]));
    float s = 0.0f;
    for (int i = tid; i < L_; i += 256) s += __expf(row[i] - M);
    s = waveSum(s);
    if ((tid & 63) == 0) red[4 + (tid >> 6)] = s;
    __syncthreads();
    if (tid == 0) {
        stats[bh * 2]     = M;
        stats[bh * 2 + 1] = red[4] + red[5] + red[6] + red[7];
    }
}

// ---------------- K3: in-place A = softmax, BW, AAT upper-tri partials (atomic) -------
__global__ __launch_bounds__(256)
void k3_soft(float* __restrict__ out, const float* __restrict__ stats, float* __restrict__ aat)
{
    const int blk = blockIdx.x;        // 256 blocks, 4 per batch
    const int b   = blk >> 2;
    const int l0  = (blk & 3) << 10;   // 1024 l's each
    const int tid = threadIdx.x;
    float* A0 = out + OFF_A + (size_t)b * HOPS * L_;
    float* BW = out + (size_t)b * L_;
    float M[HOPS], R[HOPS];
    #pragma unroll
    for (int hh = 0; hh < HOPS; ++hh) {
        M[hh] = stats[(b * HOPS + hh) * 2];
        R[hh] = 1.0f / stats[(b * HOPS + hh) * 2 + 1];
    }
    float p[36];
    #pragma unroll
    for (int i = 0; i < 36; ++i) p[i] = 0.0f;
    for (int l = l0 + tid; l < l0 + 1024; l += 256) {
        float e[HOPS]; float srow = 0.0f;
        #pragma unroll
        for (int hh = 0; hh < HOPS; ++hh) {
            float v = __expf(A0[hh * L_ + l] - M[hh]) * R[hh];
            e[hh] = v; srow += v;
        }
        #pragma unroll
        for (int hh = 0; hh < HOPS; ++hh) A0[hh * L_ + l] = e[hh];
        BW[l] = srow;
        int i = 0;
        #pragma unroll
        for (int hh = 0; hh < HOPS; ++hh) {
            #pragma unroll
            for (int gg = hh; gg < HOPS; ++gg) { p[i] = fmaf(e[hh], e[gg], p[i]); ++i; }
        }
    }
    #pragma unroll
    for (int i = 0; i < 36; ++i) p[i] = waveSum(p[i]);
    __shared__ float red[4][36];
    const int wv = tid >> 6, ln = tid & 63;
    if (ln == 0) {
        #pragma unroll
        for (int i = 0; i < 36; ++i) red[wv][i] = p[i];
    }
    __syncthreads();
    if (tid < 36) {
        float s = red[0][tid] + red[1][tid] + red[2][tid] + red[3][tid];
        atomicAdd(&aat[b * 36 + tid], s);
    }
}

// ---------------- K4: penal = sum_b sum((AAT_b - I)^2), off-diag counted twice --------
__global__ __launch_bounds__(256)
void k4_penal(const float* __restrict__ aat, float* __restrict__ out)
{
    const int tid = threadIdx.x;
    float s = 0.0f;
    for (int i = tid; i < B_ * 36; i += 256) {
        int r = i % 36;
        bool dg = (r == 0) | (r == 8) | (r == 15) | (r == 21) |
                  (r == 26) | (r == 30) | (r == 33) | (r == 35);
        float d = aat[i] - (dg ? 1.0f : 0.0f);
        float qd = d * d;
        s += dg ? qd : 2.0f * qd;
    }
    s = waveSum(s);
    __shared__ float red[4];
    if ((tid & 63) == 0) red[tid >> 6] = s;
    __syncthreads();
    if (tid == 0) out[OFF_PENAL] = red[0] + red[1] + red[2] + red[3];
}

extern "C" void kernel_launch(void* const* d_in, const int* in_sizes, int n_in,
                              void* d_out, int out_size, void* d_ws, size_t ws_size,
                              hipStream_t stream) {
    const float* node  = (const float*)d_in[0];
    const float* neigh = (const float*)d_in[1];
    const int*   nnum  = (const int*)d_in[2];   // low 32 bits of elem 0 (LE, value in [1,64))
    const float* W1    = (const float*)d_in[3];
    const float* b1    = (const float*)d_in[4];
    const float* W2    = (const float*)d_in[5];
    const float* b2    = (const float*)d_in[6];
    float* out   = (float*)d_out;
    float* stats = (float*)d_ws;          // 512*2 floats
    float* aat   = stats + 1024;          // 64*36 floats (upper-tri, accumulated)

    k1_mfma <<<B_ * 16, 256, 0, stream>>>(node, neigh, nnum, W1, b1, W2, b2, out);
    k2_stats<<<B_ * HOPS, 256, 0, stream>>>(out, stats, aat);
    k3_soft <<<256, 256, 0, stream>>>(out, stats, aat);
    k4_penal<<<1, 256, 0, stream>>>(aat, out);
}

// Round 8
// 92.799 us; speedup vs baseline: 1.5555x; 1.5555x over previous
//
#include <hip/hip_runtime.h>
#include <hip/hip_bf16.h>
#include <math.h>

#define HID 128
#define ATT 64
#define HOPS 8
#define T_ 64
#define N_ 64
#define B_ 64
#define L_ 4096

typedef __attribute__((ext_vector_type(8))) short bf16x8;
typedef __attribute__((ext_vector_type(4))) float f32x4;

static constexpr size_t OFF_A     = (size_t)B_ * N_ * T_;              // 262144
static constexpr size_t OFF_NEIGH = OFF_A + (size_t)B_ * HOPS * L_;    // 2359296
static constexpr size_t OFF_PENAL = OFF_NEIGH + (size_t)B_ * L_ * HID; // 35913728

__device__ __forceinline__ unsigned pkbf(float lo, float hi) {
    unsigned a = (unsigned)(unsigned short)__builtin_bit_cast(unsigned short, __float2bfloat16(lo));
    unsigned b = (unsigned)(unsigned short)__builtin_bit_cast(unsigned short, __float2bfloat16(hi));
    return a | (b << 16);
}
__device__ __forceinline__ short f2bf(float x) {
    return __builtin_bit_cast(short, __float2bfloat16(x));
}
__device__ __forceinline__ float bflo(unsigned u) { return __builtin_bit_cast(float, u << 16); }
__device__ __forceinline__ float bfhi(unsigned u) { return __builtin_bit_cast(float, u & 0xffff0000u); }

// LDS-only barrier: waits own ds_writes, does NOT drain vmcnt -> global loads
// stay in flight across it (T3/T4 pattern).
__device__ __forceinline__ void lds_barrier() {
    asm volatile("s_waitcnt lgkmcnt(0)" ::: "memory");
    __builtin_amdgcn_s_barrier();
}

// ---------------- K1: per-wave strips, 1KB-contiguous wave streams, private-LDS
// transpose, MFMA s1->tanh->s2. 512 thr (8 waves), grid 512 = 2 blocks/CU resident,
// 16 independent waves/CU; ONE barrier total (W1 publish).
// Strip = 16 rows x 128 f32. Load instr j: lane covers rows 2j+(lane>>5), bytes
// (lane&31)*16 of the 2-row 1KB span -> fully coalesced, full 256B granules.
__global__ __launch_bounds__(512, 4)
void k1_mfma(const float* __restrict__ node, const float* __restrict__ neigh,
             const int* __restrict__ nnum, const float* __restrict__ W1,
             const float* __restrict__ b1, const float* __restrict__ W2,
             const float* __restrict__ b2, float* __restrict__ out)
{
    __shared__ __align__(16) unsigned w1lds[64 * 68];        // 17.0 KB  W1 bf16 pairs [a][kp]
    __shared__ __align__(16) unsigned hlds [8 * 16 * 68];    // 34.0 KB  per-wave H tiles
    __shared__ __align__(16) short    thlds[8 * 16 * 72];    // 18.0 KB  per-wave tanh tiles

    const int tid  = threadIdx.x;
    const int w    = tid >> 6;
    const int lane = tid & 63;
    const int c    = lane & 15;
    const int g    = lane >> 4;
    const int ro   = lane >> 5;          // row parity within 2-row span
    const int p    = lane & 31;          // 16B piece within the 1KB span

    const int b = blockIdx.x >> 3;
    const int q = ((blockIdx.x & 7) << 3) | w;     // wave's strip id (0..63) in batch

    const size_t sbase = ((size_t)b * L_ + (size_t)q * 16) * HID;
    const float* npb = neigh + sbase;
    float*       cpb = out + OFF_NEIGH + sbase;
    float*       s2b = out + OFF_A + (size_t)b * HOPS * L_;

    // ---- prologue loads: strip 0, both halves, in flight across all staging ----
    float4 bufA[4], bufB[4];
    #pragma unroll
    for (int j = 0; j < 4; ++j)
        bufA[j] = *(const float4*)(npb + (2 * j + ro) * HID + p * 4);
    #pragma unroll
    for (int j = 0; j < 4; ++j)
        bufB[j] = *(const float4*)(npb + (2 * (j + 4) + ro) * HID + p * 4);

    // ---- stage W1 -> LDS bf16 (256 threads) ----
    if (tid < 256) {
        const int a = tid >> 2, qq = tid & 3;
        const float* src = W1 + a * HID + qq * 32;
        float x[32];
        #pragma unroll
        for (int i = 0; i < 8; ++i) *(float4*)&x[i * 4] = *(const float4*)(src + i * 4);
        unsigned* dst = &w1lds[a * 68 + qq * 16];
        #pragma unroll
        for (int i = 0; i < 16; ++i) dst[i] = pkbf(x[2 * i], x[2 * i + 1]);
    }

    // ---- node rows for this wave, packed bf16 (rows (w&3)*16 .. +15) ----
    uint2 npk[8];
    {
        const float* ndw = node + ((size_t)b * T_ + (w & 3) * 16) * HID;
        #pragma unroll
        for (int j = 0; j < 8; ++j) {
            float4 nv = *(const float4*)(ndw + (2 * j + ro) * HID + p * 4);
            npk[j].x = pkbf(nv.x, nv.y);
            npk[j].y = pkbf(nv.z, nv.w);
        }
    }

    // ---- W2 B-fragments in registers; b1/b2 ----
    bf16x8 wf2[2];
    #pragma unroll
    for (int ks2 = 0; ks2 < 2; ++ks2) {
        union { bf16x8 vv; unsigned u[4]; } t;
        #pragma unroll
        for (int i = 0; i < 4; ++i) {
            float lo = (c < 8) ? W2[c * 64 + ks2 * 32 + g * 8 + 2 * i]     : 0.f;
            float hi = (c < 8) ? W2[c * 64 + ks2 * 32 + g * 8 + 2 * i + 1] : 0.f;
            t.u[i] = pkbf(lo, hi);
        }
        wf2[ks2] = t.vv;
    }
    float b1v[4];
    #pragma unroll
    for (int cf = 0; cf < 4; ++cf) b1v[cf] = b1[cf * 16 + c];
    const float b2v = (c < 8) ? b2[c] : 0.f;
    const float inv_scale = rsqrtf((float)nnum[0]);

    lds_barrier();                        // publish W1; loads survive

    const unsigned* w1p = &w1lds[c * 68 + g * 4];
    unsigned*       hw  = &hlds[w * 1088];
    const unsigned* hr  = &hlds[w * 1088 + c * 68 + g * 4];
    short*          thw = &thlds[w * 1152];

    #pragma unroll
    for (int k = 0; k < 4; ++k) {
        const float* nx = npb + (size_t)(k + 1) * 1024 * HID;
        float*       cd = cpb + (size_t)k * 1024 * HID;

        // ---- half 0 (rows 0..7), bufA ----
        {
            uint2 hp[4];
            #pragma unroll
            for (int j = 0; j < 4; ++j) {
                const float n0 = bflo(npk[j].x), n1 = bfhi(npk[j].x);
                const float n2 = bflo(npk[j].y), n3 = bfhi(npk[j].y);
                hp[j].x = pkbf(bufA[j].x * n0, bufA[j].y * n1);
                hp[j].y = pkbf(bufA[j].z * n2, bufA[j].w * n3);
            }
            #pragma unroll
            for (int j = 0; j < 4; ++j)
                *(uint2*)&hw[(2 * j + ro) * 68 + 2 * p] = hp[j];
            #pragma unroll
            for (int j = 0; j < 4; ++j)
                *(float4*)(cd + (2 * j + ro) * HID + p * 4) = bufA[j];   // bit-exact copy
            if (k < 3) {
                #pragma unroll
                for (int j = 0; j < 4; ++j)
                    bufA[j] = *(const float4*)(nx + (2 * j + ro) * HID + p * 4);
            }
        }
        // ---- half 1 (rows 8..15), bufB ----
        {
            uint2 hp[4];
            #pragma unroll
            for (int j = 0; j < 4; ++j) {
                const float n0 = bflo(npk[j + 4].x), n1 = bfhi(npk[j + 4].x);
                const float n2 = bflo(npk[j + 4].y), n3 = bfhi(npk[j + 4].y);
                hp[j].x = pkbf(bufB[j].x * n0, bufB[j].y * n1);
                hp[j].y = pkbf(bufB[j].z * n2, bufB[j].w * n3);
            }
            #pragma unroll
            for (int j = 0; j < 4; ++j)
                *(uint2*)&hw[(2 * (j + 4) + ro) * 68 + 2 * p] = hp[j];
            #pragma unroll
            for (int j = 0; j < 4; ++j)
                *(float4*)(cd + (2 * (j + 4) + ro) * HID + p * 4) = bufB[j];
            if (k < 3) {
                #pragma unroll
                for (int j = 0; j < 4; ++j)
                    bufB[j] = *(const float4*)(nx + (2 * (j + 4) + ro) * HID + p * 4);
            }
        }

        // ---- s1 GEMM: private-LDS A-frags x W1 B-frags, 16 MFMA ----
        bf16x8 af[4];
        #pragma unroll
        for (int ks = 0; ks < 4; ++ks)
            af[ks] = *reinterpret_cast<const bf16x8*>(hr + ks * 16);
        f32x4 acc[4];
        #pragma unroll
        for (int cf = 0; cf < 4; ++cf) acc[cf] = (f32x4){0.f, 0.f, 0.f, 0.f};
        #pragma unroll
        for (int cf = 0; cf < 4; ++cf) {
            #pragma unroll
            for (int ks = 0; ks < 4; ++ks) {
                const bf16x8 wf = *reinterpret_cast<const bf16x8*>(w1p + cf * 1088 + ks * 16);
                acc[cf] = __builtin_amdgcn_mfma_f32_16x16x32_bf16(af[ks], wf, acc[cf], 0, 0, 0);
            }
        }

        // ---- tanh -> per-wave LDS tile ----
        #pragma unroll
        for (int cf = 0; cf < 4; ++cf) {
            #pragma unroll
            for (int jj = 0; jj < 4; ++jj) {
                float th = (acc[cf][jj] + b1v[cf]) * inv_scale;
                th = 1.0f - 2.0f / (__expf(2.0f * th) + 1.0f);   // tanh, inf-safe
                thw[(g * 4 + jj) * 72 + cf * 16 + c] = f2bf(th);
            }
        }
        // ---- s2 MFMA + store ----
        f32x4 acc2 = (f32x4){0.f, 0.f, 0.f, 0.f};
        #pragma unroll
        for (int ks2 = 0; ks2 < 2; ++ks2) {
            bf16x8 pa = *reinterpret_cast<const bf16x8*>(&thw[c * 72 + ks2 * 32 + g * 8]);
            acc2 = __builtin_amdgcn_mfma_f32_16x16x32_bf16(pa, wf2[ks2], acc2, 0, 0, 0);
        }
        if (c < 8) {
            float4 o;
            o.x = acc2[0] + b2v; o.y = acc2[1] + b2v;
            o.z = acc2[2] + b2v; o.w = acc2[3] + b2v;
            *(float4*)&s2b[(size_t)c * L_ + q * 16 + k * 1024 + g * 4] = o;
        }
    }
}

// ---------------- reductions helpers ----------------
__device__ __forceinline__ float waveMax(float v) {
    #pragma unroll
    for (int o = 32; o > 0; o >>= 1) v = fmaxf(v, __shfl_xor(v, o));
    return v;
}
__device__ __forceinline__ float waveSum(float v) {
    #pragma unroll
    for (int o = 32; o > 0; o >>= 1) v += __shfl_xor(v, o);
    return v;
}

// ---------------- K2: per-(b,h) softmax stats + zero aat accumulators ----------------
__global__ __launch_bounds__(256)
void k2_stats(const float* __restrict__ out, float* __restrict__ stats, float* __restrict__ aat)
{
    const int bh = blockIdx.x;                         // 0..511
    const int tid = threadIdx.x;
    if (bh == 0) {
        for (int i = tid; i < B_ * 36; i += 256) aat[i] = 0.f;
    }
    const float* row = out + OFF_A + (size_t)bh * L_;
    __shared__ float red[8];
    float m = -3.4e38f;
    for (int i = tid; i < L_; i += 256) m = fmaxf(m, row[i]);
    m = waveMax(m);
    if ((tid & 63) == 0) red[tid >> 6] = m;
    __syncthreads();
    const float M = fmaxf(fmaxf(red[0], red[1]), fmaxf(red[2], red[3]));
    float s = 0.0f;
    for (int i = tid; i < L_; i += 256) s += __expf(row[i] - M);
    s = waveSum(s);
    if ((tid & 63) == 0) red[4 + (tid >> 6)] = s;
    __syncthreads();
    if (tid == 0) {
        stats[bh * 2]     = M;
        stats[bh * 2 + 1] = red[4] + red[5] + red[6] + red[7];
    }
}

// ---------------- K3: in-place A = softmax, BW, AAT upper-tri partials (atomic) -------
__global__ __launch_bounds__(256)
void k3_soft(float* __restrict__ out, const float* __restrict__ stats, float* __restrict__ aat)
{
    const int blk = blockIdx.x;        // 256 blocks, 4 per batch
    const int b   = blk >> 2;
    const int l0  = (blk & 3) << 10;   // 1024 l's each
    const int tid = threadIdx.x;
    float* A0 = out + OFF_A + (size_t)b * HOPS * L_;
    float* BW = out + (size_t)b * L_;
    float M[HOPS], R[HOPS];
    #pragma unroll
    for (int hh = 0; hh < HOPS; ++hh) {
        M[hh] = stats[(b * HOPS + hh) * 2];
        R[hh] = 1.0f / stats[(b * HOPS + hh) * 2 + 1];
    }
    float p[36];
    #pragma unroll
    for (int i = 0; i < 36; ++i) p[i] = 0.0f;
    for (int l = l0 + tid; l < l0 + 1024; l += 256) {
        float e[HOPS]; float srow = 0.0f;
        #pragma unroll
        for (int hh = 0; hh < HOPS; ++hh) {
            float v = __expf(A0[hh * L_ + l] - M[hh]) * R[hh];
            e[hh] = v; srow += v;
        }
        #pragma unroll
        for (int hh = 0; hh < HOPS; ++hh) A0[hh * L_ + l] = e[hh];
        BW[l] = srow;
        int i = 0;
        #pragma unroll
        for (int hh = 0; hh < HOPS; ++hh) {
            #pragma unroll
            for (int gg = hh; gg < HOPS; ++gg) { p[i] = fmaf(e[hh], e[gg], p[i]); ++i; }
        }
    }
    #pragma unroll
    for (int i = 0; i < 36; ++i) p[i] = waveSum(p[i]);
    __shared__ float red[4][36];
    const int wv = tid >> 6, ln = tid & 63;
    if (ln == 0) {
        #pragma unroll
        for (int i = 0; i < 36; ++i) red[wv][i] = p[i];
    }
    __syncthreads();
    if (tid < 36) {
        float s = red[0][tid] + red[1][tid] + red[2][tid] + red[3][tid];
        atomicAdd(&aat[b * 36 + tid], s);
    }
}

// ---------------- K4: penal = sum_b sum((AAT_b - I)^2), off-diag counted twice --------
__global__ __launch_bounds__(256)
void k4_penal(const float* __restrict__ aat, float* __restrict__ out)
{
    const int tid = threadIdx.x;
    float s = 0.0f;
    for (int i = tid; i < B_ * 36; i += 256) {
        int r = i % 36;
        bool dg = (r == 0) | (r == 8) | (r == 15) | (r == 21) |
                  (r == 26) | (r == 30) | (r == 33) | (r == 35);
        float d = aat[i] - (dg ? 1.0f : 0.0f);
        float qd = d * d;
        s += dg ? qd : 2.0f * qd;
    }
    s = waveSum(s);
    __shared__ float red[4];
    if ((tid & 63) == 0) red[tid >> 6] = s;
    __syncthreads();
    if (tid == 0) out[OFF_PENAL] = red[0] + red[1] + red[2] + red[3];
}

extern "C" void kernel_launch(void* const* d_in, const int* in_sizes, int n_in,
                              void* d_out, int out_size, void* d_ws, size_t ws_size,
                              hipStream_t stream) {
    const float* node  = (const float*)d_in[0];
    const float* neigh = (const float*)d_in[1];
    const int*   nnum  = (const int*)d_in[2];   // low 32 bits of elem 0 (LE, value in [1,64))
    const float* W1    = (const float*)d_in[3];
    const float* b1    = (const float*)d_in[4];
    const float* W2    = (const float*)d_in[5];
    const float* b2    = (const float*)d_in[6];
    float* out   = (float*)d_out;
    float* stats = (float*)d_ws;          // 512*2 floats
    float* aat   = stats + 1024;          // 64*36 floats (upper-tri, accumulated)

    k1_mfma <<<B_ * 8, 512, 0, stream>>>(node, neigh, nnum, W1, b1, W2, b2, out);
    k2_stats<<<B_ * HOPS, 256, 0, stream>>>(out, stats, aat);
    k3_soft <<<256, 256, 0, stream>>>(out, stats, aat);
    k4_penal<<<1, 256, 0, stream>>>(aat, out);
}